// Round 1
// 1588.411 us; speedup vs baseline: 1.6344x; 1.6344x over previous
//
#include <hip/hip_runtime.h>

#define T_STEPS 60
#define WARMUP  29
#define HID     32
#define CT      240   // 4 * T_STEPS

__device__ __forceinline__ float fexp2(float x) { return __builtin_amdgcn_exp2f(x); }
__device__ __forceinline__ float frcp(float x)  { return __builtin_amdgcn_rcpf(x); }
__device__ __forceinline__ float sigmoid_f(float x) {
    return frcp(1.0f + fexp2(-1.4426950408889634f * x));
}
__device__ __forceinline__ float tanh_f(float x) {
    float e = fexp2(2.8853900817779268f * x);
    return 1.0f - 2.0f * frcp(e + 1.0f);
}

// Broadcast the value held by lane K of each 32-lane half to all lanes of that
// half. ds_swizzle BitMode: src = ((lane & and) | or) ^ xor with and=0, or=K,
// xor=0 -> offset = K<<5. Register-only, no LDS storage, bit-exact move.
template<int K>
__device__ __forceinline__ float bcast(float x) {
    return __int_as_float(__builtin_amdgcn_ds_swizzle(__float_as_int(x), (K << 5)));
}

#define GATHER32(v, x) do { \
    v[0]  = bcast<0>(x);  v[1]  = bcast<1>(x);  v[2]  = bcast<2>(x);  v[3]  = bcast<3>(x);  \
    v[4]  = bcast<4>(x);  v[5]  = bcast<5>(x);  v[6]  = bcast<6>(x);  v[7]  = bcast<7>(x);  \
    v[8]  = bcast<8>(x);  v[9]  = bcast<9>(x);  v[10] = bcast<10>(x); v[11] = bcast<11>(x); \
    v[12] = bcast<12>(x); v[13] = bcast<13>(x); v[14] = bcast<14>(x); v[15] = bcast<15>(x); \
    v[16] = bcast<16>(x); v[17] = bcast<17>(x); v[18] = bcast<18>(x); v[19] = bcast<19>(x); \
    v[20] = bcast<20>(x); v[21] = bcast<21>(x); v[22] = bcast<22>(x); v[23] = bcast<23>(x); \
    v[24] = bcast<24>(x); v[25] = bcast<25>(x); v[26] = bcast<26>(x); v[27] = bcast<27>(x); \
    v[28] = bcast<28>(x); v[29] = bcast<29>(x); v[30] = bcast<30>(x); v[31] = bcast<31>(x); \
} while (0)

// One GRU step. Accumulation order bitwise-matches the previous (passing)
// kernel: bias add first, then k=0..3 over w_ih, then k=0..31 over w_hh, each
// gate a single sequential fma chain; projection is the same sequential chain.
#define GRU_STEP() do {                                                        \
    float gr = bgr, gz = bgz, gni = bgni, gnh = bgnh;                          \
    _Pragma("unroll")                                                          \
    for (int c = 0; c < 4; ++c) {                                              \
        gr  = __builtin_fmaf(wir[c], u[c], gr);                                \
        gz  = __builtin_fmaf(wiz[c], u[c], gz);                                \
        gni = __builtin_fmaf(win[c], u[c], gni);                               \
    }                                                                          \
    _Pragma("unroll")                                                          \
    for (int k = 0; k < HID; ++k) {                                            \
        gr  = __builtin_fmaf(whr[k], v[k], gr);                                \
        gz  = __builtin_fmaf(whz[k], v[k], gz);                                \
        gnh = __builtin_fmaf(whn[k], v[k], gnh);                               \
    }                                                                          \
    float r = sigmoid_f(gr);                                                   \
    float z = sigmoid_f(gz);                                                   \
    float n = tanh_f(__builtin_fmaf(r, gnh, gni));                             \
    x = __builtin_fmaf(z, x - n, n);                                           \
    GATHER32(v, x);                                                            \
    o = bl;                                                                    \
    _Pragma("unroll")                                                          \
    for (int k = 0; k < HID; ++k) o = __builtin_fmaf(wlr[k], v[k], o);         \
} while (0)

// Lane j of each 32-lane half owns hidden unit j of one batch element.
// All weights live permanently in VGPRs; the recurrence runs with zero memory
// traffic except 4 input loads/step (warmup) and the 8-lane output store.
__global__ __launch_bounds__(256, 2) void gru_fused(
    const float* __restrict__ in,
    const float* __restrict__ w_ih,  const float* __restrict__ w_hh,
    const float* __restrict__ b_ih,  const float* __restrict__ b_hh,
    const float* __restrict__ w_lin, const float* __restrict__ b_lin,
    float* __restrict__ out, float* __restrict__ h28out, int B)
{
    const int lane = threadIdx.x & 63;
    const int j    = lane & 31;                 // hidden unit owned by this lane
    const int wv   = threadIdx.x >> 6;          // wave index in block
    const int s    = lane >> 5;                 // batch slot within wave
    const int b    = blockIdx.x * 8 + wv * 2 + s;

    // ---- one-time: load resident weights (rows of this lane's hidden unit) ----
    float whr[HID], whz[HID], whn[HID], wlr[HID];
    float wir[4], wiz[4], win[4];
    {
        const float4* pr = (const float4*)(w_hh + (size_t)j * HID);
        const float4* pz = (const float4*)(w_hh + (size_t)(HID + j) * HID);
        const float4* pn = (const float4*)(w_hh + (size_t)(2 * HID + j) * HID);
        const float4* pl = (const float4*)(w_lin + (size_t)(j & 3) * HID);
#pragma unroll
        for (int q = 0; q < 8; ++q) {
            float4 a = pr[q];
            whr[4*q] = a.x; whr[4*q+1] = a.y; whr[4*q+2] = a.z; whr[4*q+3] = a.w;
            float4 c = pz[q];
            whz[4*q] = c.x; whz[4*q+1] = c.y; whz[4*q+2] = c.z; whz[4*q+3] = c.w;
            float4 d = pn[q];
            whn[4*q] = d.x; whn[4*q+1] = d.y; whn[4*q+2] = d.z; whn[4*q+3] = d.w;
            float4 e = pl[q];
            wlr[4*q] = e.x; wlr[4*q+1] = e.y; wlr[4*q+2] = e.z; wlr[4*q+3] = e.w;
        }
        float4 a = ((const float4*)w_ih)[j];
        wir[0] = a.x; wir[1] = a.y; wir[2] = a.z; wir[3] = a.w;
        float4 c = ((const float4*)w_ih)[HID + j];
        wiz[0] = c.x; wiz[1] = c.y; wiz[2] = c.z; wiz[3] = c.w;
        float4 d = ((const float4*)w_ih)[2 * HID + j];
        win[0] = d.x; win[1] = d.y; win[2] = d.z; win[3] = d.w;
    }
    const float bgr  = b_ih[j]           + b_hh[j];
    const float bgz  = b_ih[HID + j]     + b_hh[HID + j];
    const float bgni = b_ih[2 * HID + j];
    const float bgnh = b_hh[2 * HID + j];
    const float bl   = b_lin[j & 3];

    float v[HID], u[4];
    float x = 0.0f, o = 0.0f;
#pragma unroll
    for (int k = 0; k < HID; ++k) v[k] = 0.0f;   // h0 = 0

    const float* pin  = in  + (size_t)b * CT;                    // [4][60] row
    float*       pout = out + (size_t)b * CT + (j & 3) * T_STEPS; // used when j<4

    // Phase 1: warmup — input from ground truth
#pragma unroll 1
    for (int t = 0; t < WARMUP; ++t) {
        u[0] = pin[t];
        u[1] = pin[60 + t];
        u[2] = pin[120 + t];
        u[3] = pin[180 + t];
        GRU_STEP();
        if (j < 4) pout[t] = o;
    }

    // h after step t == WARMUP-1
    h28out[(size_t)b * HID + j] = x;

    // Phase 2: feedback — input is previous step's projection (lanes 0..3 of
    // each half hold o_0..o_3; broadcast them, bit-exact)
#pragma unroll 1
    for (int t = WARMUP; t < T_STEPS; ++t) {
        u[0] = bcast<0>(o);
        u[1] = bcast<1>(o);
        u[2] = bcast<2>(o);
        u[3] = bcast<3>(o);
        GRU_STEP();
        if (j < 4) pout[t] = o;
    }
}

extern "C" void kernel_launch(void* const* d_in, const int* in_sizes, int n_in,
                              void* d_out, int out_size, void* d_ws, size_t ws_size,
                              hipStream_t stream) {
    const float* input = (const float*)d_in[0];
    const float* w_ih  = (const float*)d_in[1];
    const float* w_hh  = (const float*)d_in[2];
    const float* b_ih  = (const float*)d_in[3];
    const float* b_hh  = (const float*)d_in[4];
    const float* w_lin = (const float*)d_in[5];
    const float* b_lin = (const float*)d_in[6];

    const int B = in_sizes[0] / CT;          // 131072
    float* out = (float*)d_out;              // [B][240]
    float* h28 = out + (size_t)B * CT;       // [B][32]
    (void)d_ws; (void)ws_size;

    hipLaunchKernelGGL(gru_fused, dim3(B / 8), dim3(256), 0, stream,
                       input, w_ih, w_hh, b_ih, b_hh, w_lin, b_lin, out, h28, B);
}